// Round 4
// baseline (442.411 us; speedup 1.0000x reference)
//
#include <hip/hip_runtime.h>

#define N 8192
#define D 128
#define MAXNZ 256          // per-row cap (mean 82, sigma 9; P(>256) ~ 0)
#define NZCAP (1 << 20)    // flat worklist capacity (expect ~672K)

// Native clang vector type — __builtin_nontemporal_load requires scalar/vector-of-scalar.
typedef float nt_float4 __attribute__((ext_vector_type(4)));

// ws layout (bytes):
//   [0, 4MB)              Y = W + b           (8192 x 128 f32)
//   [4MB, 20MB)           nzbuf int4[NZCAP]   (i, j, bits(a), 0)
//   [20MB, 20MB+16KB)     partials[4096]      ([0,2048) = K1 reg, [2048,4096) = K2 main)
//   [20MB+16KB, +4)       gcnt
#define Y_OFF     0
#define NZ_OFF    (4u * 1024 * 1024)
#define PART_OFF  (20u * 1024 * 1024)
#define GCNT_OFF  (PART_OFF + 4096u * 4)

__device__ __forceinline__ float wave_reduce(float p) {
    #pragma unroll
    for (int off = 32; off > 0; off >>= 1)
        p += __shfl_xor(p, off, 64);
    return p;
}

__global__ void gf_init_kernel(int* gcnt) { *gcnt = 0; }

// K1: pure streaming regime. One wave per row: nt-stream A[row,:], ballot-compact
// nonzeros into LDS, emit flat (i,j,a) triplets to the global worklist, write
// Y=W+b, bank the reg term. No dependent gathers -> every resident wave keeps
// 4 float4 loads in flight -> HBM-BW-bound.
__global__ __launch_bounds__(256, 6)
void gf_stream_kernel(const float* __restrict__ A,
                      const float* __restrict__ W,
                      const float* __restrict__ b,
                      float* __restrict__ Y,
                      int4* __restrict__ nzbuf,
                      float* __restrict__ partials,
                      int* __restrict__ gcnt) {
    __shared__ int   s_col[4][MAXNZ];
    __shared__ float s_val[4][MAXNZ];
    __shared__ float s_bsum[4];

    const int lane = threadIdx.x & 63;
    const int w    = threadIdx.x >> 6;
    const int row  = blockIdx.x * 4 + w;

    const float2 bb = ((const float2*)b)[lane];
    float2 yi = ((const float2*)(W + (size_t)row * D))[lane];
    yi.x += bb.x; yi.y += bb.y;
    ((float2*)(Y + (size_t)row * D))[lane] = yi;     // cache-resident store for K2

    const nt_float4* Arow = (const nt_float4*)(A + (size_t)row * N);
    const unsigned long long lmask = (1ull << lane) - 1ull;

    nt_float4 pf[4];
    #pragma unroll
    for (int k = 0; k < 4; ++k) pf[k] = __builtin_nontemporal_load(&Arow[k * 64 + lane]);

    int cnt = 0;
    for (int it = 0; it < 8; ++it) {          // 8 macro-iters x 4 chunks = 32
        nt_float4 cur[4];
        #pragma unroll
        for (int k = 0; k < 4; ++k) cur[k] = pf[k];
        if (it < 7) {
            #pragma unroll
            for (int k = 0; k < 4; ++k)
                pf[k] = __builtin_nontemporal_load(&Arow[(it + 1) * 256 + k * 64 + lane]);
        }
        #pragma unroll
        for (int k = 0; k < 4; ++k) {
            const int base_col = (it * 4 + k) * 256 + lane * 4;
            const float av4[4] = {cur[k].x, cur[k].y, cur[k].z, cur[k].w};
            #pragma unroll
            for (int q = 0; q < 4; ++q) {
                const unsigned long long m = __ballot(av4[q] > 0.0f);
                if (av4[q] > 0.0f) {
                    const int pos = cnt + __popcll(m & lmask);
                    if (pos < MAXNZ) {
                        s_col[w][pos] = base_col + q;
                        s_val[w][pos] = av4[q];
                    }
                }
                cnt += __popcll(m);
            }
        }
    }
    if (cnt > MAXNZ) cnt = MAXNZ;

    // Reserve a contiguous span in the flat worklist; cooperative copy-out.
    int base = 0;
    if (lane == 0) base = atomicAdd(gcnt, cnt);
    base = __shfl(base, 0, 64);
    if (base + cnt > NZCAP) cnt = NZCAP - base;      // never in practice
    for (int t = lane; t < cnt; t += 64)
        nzbuf[base + t] = make_int4(row, s_col[w][t], __float_as_int(s_val[w][t]), 0);

    const float reg = wave_reduce(yi.x * yi.x + yi.y * yi.y);
    if (lane == 0) s_bsum[w] = 0.05f * reg;          // LMBD/2
    __syncthreads();
    if (threadIdx.x == 0)
        partials[blockIdx.x] = s_bsum[0] + s_bsum[1] + s_bsum[2] + s_bsum[3];
}

// K2: pure gather/compute regime. Grid-stride over the flat worklist; a 16-lane
// quarter-wave computes each 128-dot (8 floats/lane, shuffle depth 4). 2-deep
// pipeline: triplets fetched 2 iterations ahead, Y rows 1 iteration ahead, so
// the L2/L3 gather latency hides under the previous dot's FMA+shuffle work.
__global__ __launch_bounds__(256, 6)
void gf_dot_kernel(const float* __restrict__ Y,
                   const int4* __restrict__ nzbuf,
                   const int* __restrict__ gcnt,
                   float* __restrict__ partials) {
    __shared__ float s_bsum[4];
    const int lane = threadIdx.x & 63;
    const int w    = threadIdx.x >> 6;
    const int s    = lane & 15;

    const int total  = min(*gcnt, NZCAP);
    const int stride = gridDim.x * 16;               // quarters in grid
    const int qid    = blockIdx.x * 16 + w * 4 + (lane >> 4);

    float acc = 0.0f;
    int4 nzA, nzB;
    float4 yiA0, yiA1, yjA0, yjA1;
    {
        const int iA = (qid < total) ? qid : 0;
        nzA = nzbuf[iA];
        const int iB = (qid + stride < total) ? (qid + stride) : 0;
        nzB = nzbuf[iB];
        const float* Yi = Y + (size_t)(nzA.x & (N - 1)) * D;
        const float* Yj = Y + (size_t)(nzA.y & (N - 1)) * D;
        yiA0 = ((const float4*)Yi)[s * 2]; yiA1 = ((const float4*)Yi)[s * 2 + 1];
        yjA0 = ((const float4*)Yj)[s * 2]; yjA1 = ((const float4*)Yj)[s * 2 + 1];
    }

    for (int t = qid; t < total; t += stride) {
        // issue next iteration's Y gathers (from triplet fetched last iter)
        float4 yiB0, yiB1, yjB0, yjB1;
        {
            const float* Yi = Y + (size_t)(nzB.x & (N - 1)) * D;
            const float* Yj = Y + (size_t)(nzB.y & (N - 1)) * D;
            yiB0 = ((const float4*)Yi)[s * 2]; yiB1 = ((const float4*)Yi)[s * 2 + 1];
            yjB0 = ((const float4*)Yj)[s * 2]; yjB1 = ((const float4*)Yj)[s * 2 + 1];
        }
        // issue triplet two iterations ahead
        int4 nzC;
        {
            const int iC = (t + 2 * stride < total) ? (t + 2 * stride) : 0;
            nzC = nzbuf[iC];
        }
        // compute current dot
        float p = yiA0.x * yjA0.x + yiA0.y * yjA0.y + yiA0.z * yjA0.z + yiA0.w * yjA0.w
                + yiA1.x * yjA1.x + yiA1.y * yjA1.y + yiA1.z * yjA1.z + yiA1.w * yjA1.w;
        #pragma unroll
        for (int off = 8; off > 0; off >>= 1)
            p += __shfl_xor(p, off, 64);             // stays within the 16-lane quarter
        if (s == 0) {
            const float r = __int_as_float(nzA.z) - p;
            acc += r * r;
        }
        // rotate pipeline
        nzA = nzB; nzB = nzC;
        yiA0 = yiB0; yiA1 = yiB1; yjA0 = yjB0; yjA1 = yjB1;
    }

    acc = wave_reduce(acc);
    if (lane == 0) s_bsum[w] = acc;
    __syncthreads();
    if (threadIdx.x == 0)
        partials[2048 + blockIdx.x] =
            0.5f * (s_bsum[0] + s_bsum[1] + s_bsum[2] + s_bsum[3]);
}

// Sum 4096 partials -> out[0].
__global__ __launch_bounds__(256)
void gf_reduce_kernel(const float* __restrict__ partials, float* __restrict__ out) {
    __shared__ float s_ws[4];
    const int lane = threadIdx.x & 63;
    const int w    = threadIdx.x >> 6;
    float s = 0.0f;
    for (int i = threadIdx.x; i < 4096; i += 256) s += partials[i];
    s = wave_reduce(s);
    if (lane == 0) s_ws[w] = s;
    __syncthreads();
    if (threadIdx.x == 0) out[0] = s_ws[0] + s_ws[1] + s_ws[2] + s_ws[3];
}

extern "C" void kernel_launch(void* const* d_in, const int* in_sizes, int n_in,
                              void* d_out, int out_size, void* d_ws, size_t ws_size,
                              hipStream_t stream) {
    const float* A = (const float*)d_in[0];
    const float* W = (const float*)d_in[1];
    const float* b = (const float*)d_in[2];
    float* out = (float*)d_out;

    char* ws = (char*)d_ws;
    float* Y        = (float*)(ws + Y_OFF);
    int4*  nzbuf    = (int4*)(ws + NZ_OFF);
    float* partials = (float*)(ws + PART_OFF);
    int*   gcnt     = (int*)(ws + GCNT_OFF);

    gf_init_kernel<<<dim3(1), dim3(1), 0, stream>>>(gcnt);
    gf_stream_kernel<<<dim3(N / 4), dim3(256), 0, stream>>>(A, W, b, Y, nzbuf, partials, gcnt);
    gf_dot_kernel<<<dim3(2048), dim3(256), 0, stream>>>(Y, nzbuf, gcnt, partials);
    gf_reduce_kernel<<<dim3(1), dim3(256), 0, stream>>>(partials, out);
}

// Round 5
// 353.563 us; speedup vs baseline: 1.2513x; 1.2513x over previous
//
#include <hip/hip_runtime.h>

#define N 8192
#define D 128
#define MAXNZ 256   // max nonzeros per row we track (mean 82, sigma 9; P(>256) ~ 0)

// Native clang vector type — __builtin_nontemporal_load requires scalar/vector-of-scalar.
typedef float nt_float4 __attribute__((ext_vector_type(4)));

// Full-wave (64-lane) butterfly reduce; result broadcast to all lanes.
__device__ __forceinline__ float wave_reduce(float p) {
    #pragma unroll
    for (int off = 32; off > 0; off >>= 1)
        p += __shfl_xor(p, off, 64);
    return p;
}

// One wave per row, fused.
// Phase 1: nt-stream A[row,:] (4-deep float4 pipeline), ballot-compact nonzeros
//          (col,val) into LDS.
// Phase 2: QUARTER-WAVE dots — each 16-lane quarter computes one full 128-dot
//          (8 floats/lane = 2 x float4), shuffle depth 4 (offs 8,4,2,1), only
//          4 shuffle instructions per 4 nonzeros (was 24 at depth 6).
//          2-stage pipeline: cols/vals read 2 groups ahead, Y-row gathers
//          issued 1 group ahead so L2 latency hides under the current dot.
__global__ __launch_bounds__(256, 6)
void gf_main_kernel(const float* __restrict__ A,
                    const float* __restrict__ W,
                    const float* __restrict__ b,
                    float* __restrict__ partials) {
    __shared__ int   s_col[4][MAXNZ];
    __shared__ float s_val[4][MAXNZ];
    __shared__ float s_bsum[4];

    const int lane = threadIdx.x & 63;
    const int w    = threadIdx.x >> 6;
    const int row  = blockIdx.x * 4 + w;
    const int q    = lane >> 4;   // quarter id (which nonzero in the group of 4)
    const int s    = lane & 15;   // lane within quarter (which 8-float slice of D)

    // yi slice for quarter-wave dots: elements [s*8, s*8+8)
    const float4* B4   = (const float4*)b;
    const float4  b0   = B4[s * 2];
    const float4  b1   = B4[s * 2 + 1];
    const float4* Wrow = (const float4*)(W + (size_t)row * D);
    float4 yi0 = Wrow[s * 2];
    float4 yi1 = Wrow[s * 2 + 1];
    yi0.x += b0.x; yi0.y += b0.y; yi0.z += b0.z; yi0.w += b0.w;
    yi1.x += b1.x; yi1.y += b1.y; yi1.z += b1.z; yi1.w += b1.w;
    // loop-invariant: yi . b  (per-lane partial)
    const float yib = yi0.x * b0.x + yi0.y * b0.y + yi0.z * b0.z + yi0.w * b0.w
                    + yi1.x * b1.x + yi1.y * b1.y + yi1.z * b1.z + yi1.w * b1.w;

    // ---- Phase 1: compact nonzeros of this row into LDS (pipelined, nt) ----
    const nt_float4* Arow = (const nt_float4*)(A + (size_t)row * N);
    const unsigned long long lmask = (1ull << lane) - 1ull;

    nt_float4 pf[4];
    #pragma unroll
    for (int k = 0; k < 4; ++k) pf[k] = __builtin_nontemporal_load(&Arow[k * 64 + lane]);

    int cnt = 0;
    for (int it = 0; it < 8; ++it) {          // 8 macro-iters x 4 chunks = 32
        nt_float4 cur[4];
        #pragma unroll
        for (int k = 0; k < 4; ++k) cur[k] = pf[k];
        if (it < 7) {
            #pragma unroll
            for (int k = 0; k < 4; ++k)
                pf[k] = __builtin_nontemporal_load(&Arow[(it + 1) * 256 + k * 64 + lane]);
        }
        #pragma unroll
        for (int k = 0; k < 4; ++k) {
            const int base_col = (it * 4 + k) * 256 + lane * 4;
            const float av4[4] = {cur[k].x, cur[k].y, cur[k].z, cur[k].w};
            #pragma unroll
            for (int p = 0; p < 4; ++p) {
                const unsigned long long m = __ballot(av4[p] > 0.0f);
                if (av4[p] > 0.0f) {
                    const int pos = cnt + __popcll(m & lmask);
                    if (pos < MAXNZ) {
                        s_col[w][pos] = base_col + p;
                        s_val[w][pos] = av4[p];
                    }
                }
                cnt += __popcll(m);
            }
        }
    }
    if (cnt > MAXNZ) cnt = MAXNZ;
    __syncthreads();   // order LDS writes before cross-quarter reads

    // ---- Phase 2: quarter-wave dots, 2-stage pipeline ----
    float acc = 0.0f;
    int   jn;  float avc, avn;
    float4 ga0, ga1;                           // gather regs (in flight / ready)
    {   // group 0: cols + issue gather
        const int i0 = (q < cnt) ? q : 0;
        const int j0 = s_col[w][i0] & (N - 1); // mask: LDS may be garbage if cnt==0
        avc = (q < cnt) ? s_val[w][i0] : 0.0f;
        const float4* Yj = (const float4*)(W + (size_t)j0 * D);
        ga0 = Yj[s * 2]; ga1 = Yj[s * 2 + 1];
    }
    {   // group 1: cols only
        const int t1 = 4 + q;
        const int i1 = (t1 < cnt) ? t1 : 0;
        jn  = s_col[w][i1] & (N - 1);
        avn = (t1 < cnt) ? s_val[w][i1] : 0.0f;
    }

    for (int t = 0; t < cnt; t += 4) {
        const float4 yj0 = ga0, yj1 = ga1;     // current group (loads have landed)
        const float  ava = avc;
        {   // issue gather for group t+4 (cols already in regs)
            const float4* Yj = (const float4*)(W + (size_t)jn * D);
            ga0 = Yj[s * 2]; ga1 = Yj[s * 2 + 1];
        }
        {   // read cols for group t+8
            const int t2 = t + 8 + q;
            const int i2 = (t2 < cnt) ? t2 : 0;
            jn  = s_col[w][i2] & (N - 1);
            avc = avn;
            avn = (t2 < cnt) ? s_val[w][i2] : 0.0f;
        }
        // dot: yi . (yj + b) = yi.yj + yib
        float p = yi0.x * yj0.x + yi0.y * yj0.y + yi0.z * yj0.z + yi0.w * yj0.w
                + yi1.x * yj1.x + yi1.y * yj1.y + yi1.z * yj1.z + yi1.w * yj1.w
                + yib;
        #pragma unroll
        for (int off = 8; off > 0; off >>= 1)
            p += __shfl_xor(p, off, 64);       // reduce within the 16-lane quarter
        if (s == 0 && (t + q) < cnt) {
            const float r = ava - p;
            acc += r * r;
        }
    }

    // ---- Epilogue: reg term (quarter 0 covers the full row exactly once) ----
    float regp = 0.0f;
    if (q == 0)
        regp = yi0.x * yi0.x + yi0.y * yi0.y + yi0.z * yi0.z + yi0.w * yi0.w
             + yi1.x * yi1.x + yi1.y * yi1.y + yi1.z * yi1.z + yi1.w * yi1.w;
    const float total = wave_reduce(0.5f * acc + 0.05f * regp);
    if (lane == 0) s_bsum[w] = total;
    __syncthreads();
    if (threadIdx.x == 0)
        partials[blockIdx.x] = s_bsum[0] + s_bsum[1] + s_bsum[2] + s_bsum[3];
}

// Reduce 2048 block partials -> out[0]. One block, 256 threads.
__global__ __launch_bounds__(256)
void gf_reduce_kernel(const float* __restrict__ partials, float* __restrict__ out) {
    __shared__ float s_ws[4];
    const int lane = threadIdx.x & 63;
    const int w    = threadIdx.x >> 6;
    float s = 0.0f;
    for (int i = threadIdx.x; i < N / 4; i += 256) s += partials[i];
    s = wave_reduce(s);
    if (lane == 0) s_ws[w] = s;
    __syncthreads();
    if (threadIdx.x == 0) out[0] = s_ws[0] + s_ws[1] + s_ws[2] + s_ws[3];
}

extern "C" void kernel_launch(void* const* d_in, const int* in_sizes, int n_in,
                              void* d_out, int out_size, void* d_ws, size_t ws_size,
                              hipStream_t stream) {
    const float* A = (const float*)d_in[0];
    const float* W = (const float*)d_in[1];
    const float* b = (const float*)d_in[2];
    float* out = (float*)d_out;
    float* partials = (float*)d_ws;    // 2048 floats = 8 KB

    gf_main_kernel<<<dim3(N / 4), dim3(256), 0, stream>>>(A, W, b, partials);
    gf_reduce_kernel<<<dim3(1), dim3(256), 0, stream>>>(partials, out);
}